// Round 5
// baseline (384.949 us; speedup 1.0000x reference)
//
#include <hip/hip_runtime.h>
#include <hip/hip_bf16.h>

// Problem constants (b=2, n=2048, dim=1024, H=16, D=64, W=4)
#define M_TOT 4096   // b*n rows
#define DIM_  1024
#define KP    4096   // expanded K = dim*W
#define NC1   3072   // 3*H*D gemm1 gated cols
#define NC2   1024   // gemm2 gated cols (dim)

typedef unsigned short u16;
typedef unsigned int u32;
typedef unsigned long long u64;
typedef short bf16x8 __attribute__((ext_vector_type(8)));
typedef float f32x4 __attribute__((ext_vector_type(4)));

// q pre-scale: DIM_HEAD^-0.5 * log2(e)  -> S comes out of MFMA in log2 domain
#define QSCALE 0.18033688011112042f
#define EXPOFF 20.0f   // softmax shift (exact: softmax is shift-invariant)

static __device__ __forceinline__ u16 f2bf(float f) {
    union { float f; u32 u; } v; v.f = f;
    u32 u = v.u;
    u += 0x7fffu + ((u >> 16) & 1u);   // round-to-nearest-even
    return (u16)(u >> 16);
}
static __device__ __forceinline__ float bf2f(u16 h) {
    union { u32 u; float f; } v; v.u = ((u32)h) << 16; return v.f;
}

// async global->LDS, 16 B per lane; LDS dest is wave-uniform base + lane*16.
static __device__ __forceinline__ void gld_lds16(const u16* g, u16* l) {
    __builtin_amdgcn_global_load_lds(
        (__attribute__((address_space(1))) void*)(u64)g,
        (__attribute__((address_space(3))) void*)(u32)(u64)l,
        16, 0, 0);
}

// XOR-swizzle (64-col rows, 8 chunks): LDS[r][c] = G[r][c ^ (r&7)]
#define SWZ_SCOL(lane) ((((lane) & 7) ^ (((lane) >> 3) & 7)) * 8)

// raw barrier / waits: no compiler-attached vmcnt(0) drain (unlike __syncthreads)
#define RAW_BARRIER()   asm volatile("s_barrier" ::: "memory")
#define WAIT_VM0()      asm volatile("s_waitcnt vmcnt(0)" ::: "memory")
#define WAIT_VM4()      asm volatile("s_waitcnt vmcnt(4)" ::: "memory")
#define WAIT_VM6()      asm volatile("s_waitcnt vmcnt(6)" ::: "memory")
#define WAIT_LGKM0()    asm volatile("s_waitcnt lgkmcnt(0)" ::: "memory")

// ------- fused gates + A1-expand: one wave per row ---------------------------
__global__ __launch_bounds__(256) void gates_expand_kernel(const float* __restrict__ x,
                                                           const float* __restrict__ Wg,
                                                           float* __restrict__ gates,
                                                           u16* __restrict__ outA) {
    const int wid = threadIdx.x >> 6, lane = threadIdx.x & 63;
    const int m = blockIdx.x * 4 + wid;
    const float* xr = x + (size_t)m * DIM_;
    float a0 = 0.f, a1 = 0.f, a2 = 0.f, a3 = 0.f;
    for (int i = 0; i < DIM_ / 64; ++i) {
        int k = i * 64 + lane;
        float xv = xr[k];
        float4 wg = ((const float4*)Wg)[k];
        a0 += xv * wg.x; a1 += xv * wg.y; a2 += xv * wg.z; a3 += xv * wg.w;
    }
    for (int s = 1; s < 64; s <<= 1) {
        a0 += __shfl_xor(a0, s); a1 += __shfl_xor(a1, s);
        a2 += __shfl_xor(a2, s); a3 += __shfl_xor(a3, s);
    }
    float mx = fmaxf(fmaxf(a0, a1), fmaxf(a2, a3));
    float e0 = __expf(a0 - mx), e1 = __expf(a1 - mx), e2 = __expf(a2 - mx), e3 = __expf(a3 - mx);
    float inv = 1.0f / (e0 + e1 + e2 + e3);
    float g0 = e0 * inv, g1 = e1 * inv, g2 = e2 * inv, g3 = e3 * inv;
    if (lane == 0) ((float4*)gates)[m] = make_float4(g0, g1, g2, g3);
    ushort4* out4 = (ushort4*)outA;
    for (int i = 0; i < DIM_ / 64; ++i) {
        int k = i * 64 + lane;
        float val = xr[k];   // L1 hit
        ushort4 o;
        o.x = f2bf(val * g0); o.y = f2bf(val * g1); o.z = f2bf(val * g2); o.w = f2bf(val * g3);
        out4[(size_t)m * 1024 + k] = o;
    }
}

// -------- B-prep: dst[cg][r*4+w] = bf16(src[r][cg*4+w]); tile 64r x 16cg ----
// NOTE: B2 aliases B1's extent -> B2's bprep MUST launch after gemm1.
__global__ __launch_bounds__(256) void bprep_kernel(const float* __restrict__ src,
                                                    u16* __restrict__ dst,
                                                    int R, int Cg) {
    __shared__ u16 lds[64 * 68];
    const int t = threadIdx.x;
    const int cg0 = blockIdx.x * 16, k0 = blockIdx.y * 64;
    const float4* s4 = (const float4*)src;  // row stride = Cg float4s
    for (int i = 0; i < 4; ++i) {
        int f = i * 256 + t;
        int kl = f >> 4, f4 = f & 15;
        float4 v = s4[(size_t)(k0 + kl) * Cg + cg0 + f4];
        ushort4 o; o.x = f2bf(v.x); o.y = f2bf(v.y); o.z = f2bf(v.z); o.w = f2bf(v.w);
        *(ushort4*)&lds[kl * 68 + f4 * 4] = o;
    }
    __syncthreads();
    ushort4* d4 = (ushort4*)dst;  // row stride = R ushort4s
    for (int i = 0; i < 4; ++i) {
        int j = i * 256 + t;
        int cgl = j >> 6, kl = j & 63;
        d4[(size_t)(cg0 + cgl) * R + k0 + kl] = *(ushort4*)&lds[kl * 68 + cgl * 4];
    }
}

// ---------------- GEMM1: 128x128 tile, BK=64, swizzled LDS ------------------
// Round-0 proven version (142 us, 727 TF). Default blockIdx mapping KEPT:
// round-robin dispatch already gives each XCD fixed n-columns (24%8==0) ->
// B-panel 3 MB/XCD L2-resident. (XCD swizzle measured WORSE here: 217 MB
// fetch vs 160 -- do not re-add.)
__global__ __launch_bounds__(256) void gemm1_kernel(const u16* __restrict__ A,
                                                    const u16* __restrict__ Bm,
                                                    u16* __restrict__ qbuf,
                                                    u16* __restrict__ kbuf,
                                                    u16* __restrict__ vbuf) {
    __shared__ u16 lA[128 * 64];
    __shared__ u16 lB[128 * 64];
    const int t = threadIdx.x;
    const int lane = t & 63, wid = t >> 6;
    const int wm = wid >> 1, wn = wid & 1;
    const int l15 = lane & 15, quad = lane >> 4;
    const int sx = l15 & 7;
    const int n0 = blockIdx.x * 128, m0 = blockIdx.y * 128;
    const int srow = lane >> 3, scol = SWZ_SCOL(lane);
    const u16* gA = A + (size_t)(m0 + wid * 32 + srow) * KP + scol;
    const u16* gB = Bm + (size_t)(n0 + wid * 32 + srow) * KP + scol;
    u16* lAw = &lA[wid * 2048];
    u16* lBw = &lB[wid * 2048];
    f32x4 acc[4][4] = {};
    for (int k0 = 0; k0 < KP; k0 += 64) {
        for (int i = 0; i < 4; ++i)
            gld_lds16(gA + (size_t)i * 8 * KP + k0, lAw + i * 512);
        for (int i = 0; i < 4; ++i)
            gld_lds16(gB + (size_t)i * 8 * KP + k0, lBw + i * 512);
        __syncthreads();
        for (int ks = 0; ks < 2; ++ks) {
            const int co = ((ks * 4 + quad) ^ sx) * 8;
            bf16x8 af[4], bfr[4];
            for (int mt = 0; mt < 4; ++mt)
                af[mt] = *(const bf16x8*)&lA[(wm * 64 + mt * 16 + l15) * 64 + co];
            for (int nt = 0; nt < 4; ++nt)
                bfr[nt] = *(const bf16x8*)&lB[(wn * 64 + nt * 16 + l15) * 64 + co];
            for (int mt = 0; mt < 4; ++mt)
                for (int nt = 0; nt < 4; ++nt)
                    acc[mt][nt] = __builtin_amdgcn_mfma_f32_16x16x32_bf16(af[mt], bfr[nt], acc[mt][nt], 0, 0, 0);
        }
        __syncthreads();
    }
    const int qkv = n0 >> 10;
    const int base_hd = n0 & 1023;
    for (int mt = 0; mt < 4; ++mt) {
        int mrow = m0 + wm * 64 + mt * 16 + quad * 4;
        int b = mrow >> 11, n = mrow & 2047;
        int bh0 = b * 16;
        for (int nt = 0; nt < 4; ++nt) {
            int hd = base_hd + wn * 64 + nt * 16 + l15;
            int h = hd >> 6, d = hd & 63;
            int bh = bh0 + h;
            if (qkv == 0) {
                for (int r = 0; r < 4; ++r)
                    qbuf[((size_t)bh * 2048 + n + r) * 64 + d] = f2bf(acc[mt][nt][r] * QSCALE);
            } else if (qkv == 1) {
                for (int r = 0; r < 4; ++r)
                    kbuf[((size_t)bh * 2048 + n + r) * 64 + d] = f2bf(acc[mt][nt][r]);
            } else {
                ushort4 o;
                o.x = f2bf(acc[mt][nt][0]); o.y = f2bf(acc[mt][nt][1]);
                o.z = f2bf(acc[mt][nt][2]); o.w = f2bf(acc[mt][nt][3]);
                *(ushort4*)&vbuf[((size_t)bh * 64 + d) * 2048 + n] = o;
            }
        }
    }
}

// ------------- GEMM2: 128x64 tile, BK=64, RING-3 prefetch dist 2 ------------
// A2/B2 are L3-resident (~1000 cyc); the old 2-buffer gave loads only one
// ~300-cyc iteration of slack -> latency exposed every iter. Ring-3 gives 2
// iterations. Counted vmcnt(6) (6 loads/tile/wave) -- never 0 in steady state.
// Ring safety: slot (t+2)%3 == slot (t-1)%3; all its ds_reads were consumed
// (compiler lgkmcnt before MFMA) before every wave passed barrier t, and the
// stage is issued after that barrier.
__global__ __launch_bounds__(256) void gemm2_kernel(const u16* __restrict__ A,
                                                    const u16* __restrict__ Bm,
                                                    float* __restrict__ outf) {
    __shared__ u16 lA[3][128 * 64];   // 48 KB
    __shared__ u16 lB[3][64 * 64];    // 24 KB
    const int t = threadIdx.x;
    const int lane = t & 63, wid = t >> 6;
    const int wm = wid >> 1, wn = wid & 1;
    const int l15 = lane & 15, quad = lane >> 4;
    const int sx = l15 & 7;
    // XCD-bijective swizzle (grid 16x32 = 512): each XCD owns 4 m-rows ->
    // A-panels 4 MB L2-resident; B2 (8 MB) L3-shared.
    const int bid0 = blockIdx.y * 16 + blockIdx.x;
    const int nbid = (bid0 & 7) * 64 + (bid0 >> 3);
    const int n0 = (nbid & 15) * 64, m0 = (nbid >> 4) * 128;
    const int srow = lane >> 3, scol = SWZ_SCOL(lane);
    const u16* gA = A + (size_t)(m0 + wid * 32 + srow) * KP + scol;
    const u16* gB = Bm + (size_t)(n0 + wid * 16 + srow) * KP + scol;

#define G2_STAGE(tt, ss) do {                                                  \
        const int _k = (tt) * 64;                                              \
        for (int i = 0; i < 4; ++i)                                            \
            gld_lds16(gA + (size_t)i * 8 * KP + _k, &lA[ss][(wid * 32 + i * 8) * 64]); \
        for (int i = 0; i < 2; ++i)                                            \
            gld_lds16(gB + (size_t)i * 8 * KP + _k, &lB[ss][(wid * 16 + i * 8) * 64]); \
    } while (0)

    // prologue: tiles 0,1 into slots 0,1 (12 loads in flight)
    G2_STAGE(0, 0);
    G2_STAGE(1, 1);
    f32x4 acc[4][2] = {};
    int cur = 0;
    for (int it = 0; it < 64; ++it) {
        if (it < 63) WAIT_VM6();   // tile it resident; tile it+1 in flight
        else         WAIT_VM0();
        RAW_BARRIER();             // all waves resident; slot (it-1)%3 free
        if (it + 2 < 64) {
            int ns = cur + 2; if (ns >= 3) ns -= 3;
            G2_STAGE(it + 2, ns);
        }
        for (int ks = 0; ks < 2; ++ks) {
            const int co = ((ks * 4 + quad) ^ sx) * 8;
            bf16x8 af[4], bfr[2];
            for (int mt = 0; mt < 4; ++mt)
                af[mt] = *(const bf16x8*)&lA[cur][(wm * 64 + mt * 16 + l15) * 64 + co];
            for (int nt = 0; nt < 2; ++nt)
                bfr[nt] = *(const bf16x8*)&lB[cur][(wn * 32 + nt * 16 + l15) * 64 + co];
            for (int mt = 0; mt < 4; ++mt)
                for (int nt = 0; nt < 2; ++nt)
                    acc[mt][nt] = __builtin_amdgcn_mfma_f32_16x16x32_bf16(af[mt], bfr[nt], acc[mt][nt], 0, 0, 0);
        }
        cur = (cur + 1 == 3) ? 0 : cur + 1;
    }
#undef G2_STAGE
    for (int mt = 0; mt < 4; ++mt) {
        int mrow = m0 + wm * 64 + mt * 16 + quad * 4;
        for (int nt = 0; nt < 2; ++nt) {
            int col = n0 + wn * 32 + nt * 16 + l15;
            for (int r = 0; r < 4; ++r)
                outf[(size_t)(mrow + r) * NC2 + col] = acc[mt][nt][r];
        }
    }
}

// ------------- flash attention: BQ=128, BKV=64, RING-3 K/V prefetch ---------
// S^T = K Q^T; no-max exp2 softmax; wave-private lP + lgkm fence.
// Ring-3, distance-2 prefetch, counted vmcnt(4) (4 loads/tile/wave): K/V come
// from L3 (~1000 cyc); 2 iterations of slack instead of 1. Same ring-safety
// argument as gemm2. lP padded to 76 u16/row (72 gave stride-36-dword 8-way
// read conflicts; 76 -> scattered 2-way, ~free).
// Epilogue writes A2[m][k*4+w] = O[m][hd] * g[m][w] (gated expand fused).
// XCD swizzle: each XCD owns 4 consecutive bh -> K/V set 2 MB, L2-resident.
__global__ __launch_bounds__(256) void attn_kernel(const u16* __restrict__ qbuf,
                                                   const u16* __restrict__ kbuf,
                                                   const u16* __restrict__ vbuf,
                                                   const float* __restrict__ gates,
                                                   u16* __restrict__ outA) {
    __shared__ u16 lK[3][64 * 64];        // 24 KB, swizzled
    __shared__ u16 lV[3][64 * 64];        // 24 KB, swizzled
    __shared__ u16 lP[4][2 * 16 * 76];    // 19 KB: [wave][mt][i=16][j=64 pad 76]
    const int t = threadIdx.x, lane = t & 63, wq = t >> 6;
    const int l15 = lane & 15, quad = lane >> 4;
    const int sx7 = l15 & 7;
    // XCD-bijective swizzle (grid 16x32 = 512)
    const int bid0 = blockIdx.y * 16 + blockIdx.x;
    const int nbid = (bid0 & 7) * 64 + (bid0 >> 3);
    const int bh = nbid >> 4, q0 = (nbid & 15) * 128;
    const u16* Q = qbuf + (size_t)bh * 2048 * 64;
    const u16* K = kbuf + (size_t)bh * 2048 * 64;
    const u16* V = vbuf + (size_t)bh * 64 * 2048;
    // Q fragments (B-operand): direct global loads (qbuf is unswizzled)
    bf16x8 qf[2][2];
    for (int mt = 0; mt < 2; ++mt)
        for (int ks = 0; ks < 2; ++ks)
            qf[mt][ks] = *(const bf16x8*)&Q[(size_t)(q0 + wq * 32 + mt * 16 + l15) * 64 + ks * 32 + quad * 8];
    f32x4 Oa[2][4] = {};
    float lacc[2] = {0.f, 0.f};
    const int krow = lane >> 3, kcol = SWZ_SCOL(lane);
    const u16* gK = K + (size_t)(wq * 16 + krow) * 64 + kcol;
    const u16* gV = V + (size_t)(wq * 16 + krow) * 2048 + kcol;
    u16* lPw = lP[wq];

#define ATTN_STAGE(tt, ss) do {                                          \
        const size_t _o = (size_t)(tt) * 64;                             \
        gld_lds16(gK + _o * 64,               &lK[ss][(wq * 16) * 64]);     \
        gld_lds16(gK + (_o + 8) * 64,         &lK[ss][(wq * 16 + 8) * 64]); \
        gld_lds16(gV + _o,                    &lV[ss][(wq * 16) * 64]);     \
        gld_lds16(gV + _o + (size_t)8 * 2048, &lV[ss][(wq * 16 + 8) * 64]); \
    } while (0)

    // prologue: tiles 0,1 into slots 0,1 (8 loads in flight)
    ATTN_STAGE(0, 0);
    ATTN_STAGE(1, 1);
    int cur = 0;
    for (int kt = 0; kt < 32; ++kt) {
        if (kt < 31) WAIT_VM4();   // tile kt resident; tile kt+1 in flight
        else         WAIT_VM0();
        RAW_BARRIER();             // all waves resident; slot (kt-1)%3 free
        if (kt + 2 < 32) {
            int ns = cur + 2; if (ns >= 3) ns -= 3;
            ATTN_STAGE(kt + 2, ns);
        }
        // S^T = K Q^T : D[m=j][n=i]; kf shared across both mt groups
        f32x4 S[2][4] = {};
        for (int ks = 0; ks < 2; ++ks) {
            const int co = ((ks * 4 + quad) ^ sx7) * 8;
            for (int nt = 0; nt < 4; ++nt) {
                bf16x8 kf = *(const bf16x8*)&lK[cur][(nt * 16 + l15) * 64 + co];
                S[0][nt] = __builtin_amdgcn_mfma_f32_16x16x32_bf16(kf, qf[0][ks], S[0][nt], 0, 0, 0);
                S[1][nt] = __builtin_amdgcn_mfma_f32_16x16x32_bf16(kf, qf[1][ks], S[1][nt], 0, 0, 0);
            }
        }
        // P = exp2(S - EXPOFF); lane holds (j=nt*16+quad*4+r, i=l15):
        // 4 consecutive j -> one b64 write at lP[i][j] ([i][j]-major)
        for (int mt = 0; mt < 2; ++mt) {
            u16* lPm = lPw + mt * (16 * 76);
            for (int nt = 0; nt < 4; ++nt) {
                float p0 = __builtin_amdgcn_exp2f(S[mt][nt][0] - EXPOFF);
                float p1 = __builtin_amdgcn_exp2f(S[mt][nt][1] - EXPOFF);
                float p2 = __builtin_amdgcn_exp2f(S[mt][nt][2] - EXPOFF);
                float p3 = __builtin_amdgcn_exp2f(S[mt][nt][3] - EXPOFF);
                lacc[mt] += (p0 + p1) + (p2 + p3);
                uint2 pk;
                pk.x = (u32)f2bf(p0) | ((u32)f2bf(p1) << 16);
                pk.y = (u32)f2bf(p2) | ((u32)f2bf(p3) << 16);
                *(uint2*)&lPm[l15 * 76 + nt * 16 + quad * 4] = pk;
            }
        }
        WAIT_LGKM0();   // drain wave's own ds_writes (wave-private lP)
        // O += P V
        for (int ks = 0; ks < 2; ++ks) {
            const int co = ((ks * 4 + quad) ^ sx7) * 8;
            bf16x8 p0 = *(const bf16x8*)&lPw[0 * (16 * 76) + l15 * 76 + ks * 32 + quad * 8];
            bf16x8 p1 = *(const bf16x8*)&lPw[1 * (16 * 76) + l15 * 76 + ks * 32 + quad * 8];
            for (int dt = 0; dt < 4; ++dt) {
                bf16x8 vf = *(const bf16x8*)&lV[cur][(dt * 16 + l15) * 64 + co];
                Oa[0][dt] = __builtin_amdgcn_mfma_f32_16x16x32_bf16(p0, vf, Oa[0][dt], 0, 0, 0);
                Oa[1][dt] = __builtin_amdgcn_mfma_f32_16x16x32_bf16(p1, vf, Oa[1][dt], 0, 0, 0);
            }
        }
        cur = (cur + 1 == 3) ? 0 : cur + 1;
    }
#undef ATTN_STAGE
    // final row-sum reduce across quads (lanes l15, l15+16, l15+32, l15+48)
    for (int mt = 0; mt < 2; ++mt) {
        lacc[mt] += __shfl_xor(lacc[mt], 16);
        lacc[mt] += __shfl_xor(lacc[mt], 32);
    }
    const int b = bh >> 4, h = bh & 15;
    ushort4* out4 = (ushort4*)outA;
    const float4* gates4 = (const float4*)gates;
    for (int mt = 0; mt < 2; ++mt) {
        for (int r = 0; r < 4; ++r) {
            int n = q0 + wq * 32 + mt * 16 + quad * 4 + r;
            int m = b * 2048 + n;
            float invl = 1.0f / __shfl(lacc[mt], quad * 4 + r);
            float4 g = gates4[m];
            for (int dt = 0; dt < 4; ++dt) {
                float val = Oa[mt][dt][r] * invl;
                ushort4 o;
                o.x = f2bf(val * g.x); o.y = f2bf(val * g.y);
                o.z = f2bf(val * g.z); o.w = f2bf(val * g.w);
                out4[(size_t)m * 1024 + h * 64 + dt * 16 + l15] = o;
            }
        }
    }
}

extern "C" void kernel_launch(void* const* d_in, const int* in_sizes, int n_in,
                              void* d_out, int out_size, void* d_ws, size_t ws_size,
                              hipStream_t stream) {
    const float* x    = (const float*)d_in[0];
    const float* Wqkv = (const float*)d_in[1];
    const float* Wg   = (const float*)d_in[2];
    const float* Wout = (const float*)d_in[3];
    // d_in[4] = mask: all-true in this problem.

    char* ws = (char*)d_ws;
    size_t off = 0;
    float* gates = (float*)(ws + off); off += (size_t)1 << 16;                 // 64 KB
    u16* Aexp = (u16*)(ws + off);      off += (size_t)M_TOT * KP * 2;          // 32 MB (A1; attn overwrites -> A2)
    char* regB = ws + off;             off += (size_t)NC1 * KP * 2;            // 24 MB
    u16* B1 = (u16*)regB;
    u16* B2 = (u16*)(regB + (size_t)M_TOT * NC2 * 2);                          // aliases B1[8M:16M], WRITTEN AFTER GEMM1
    u16* qbuf = (u16*)(ws + off); off += (size_t)32 * 2048 * 64 * 2;           // 8 MB
    u16* kbuf = (u16*)(ws + off); off += (size_t)32 * 2048 * 64 * 2;           // 8 MB
    u16* vbuf = (u16*)(ws + off); off += (size_t)32 * 2048 * 64 * 2;           // 8 MB

    hipLaunchKernelGGL(gates_expand_kernel, dim3(1024), dim3(256), 0, stream,
                       x, Wg, gates, Aexp);
    hipLaunchKernelGGL(bprep_kernel, dim3(192, 16), dim3(256), 0, stream,
                       Wqkv, B1, 1024, 3072);
    hipLaunchKernelGGL(gemm1_kernel, dim3(24, 32), dim3(256), 0, stream,
                       Aexp, B1, qbuf, kbuf, vbuf);
    hipLaunchKernelGGL(bprep_kernel, dim3(64, 16), dim3(256), 0, stream,
                       Wout, B2, 1024, 1024);   // after gemm1: B2 overlaps B1
    hipLaunchKernelGGL(attn_kernel, dim3(16, 32), dim3(256), 0, stream,
                       qbuf, kbuf, vbuf, gates, Aexp);   // writes A2 (gated expand fused)
    hipLaunchKernelGGL(gemm2_kernel, dim3(16, 32), dim3(256), 0, stream,
                       Aexp, B2, (float*)d_out);
}

// Round 6
// 359.688 us; speedup vs baseline: 1.0702x; 1.0702x over previous
//
#include <hip/hip_runtime.h>
#include <hip/hip_bf16.h>

// Problem constants (b=2, n=2048, dim=1024, H=16, D=64, W=4)
#define M_TOT 4096   // b*n rows
#define DIM_  1024
#define KP    4096   // expanded K = dim*W
#define NC1   3072   // 3*H*D gemm1 gated cols
#define NC2   1024   // gemm2 gated cols (dim)

typedef unsigned short u16;
typedef unsigned int u32;
typedef unsigned long long u64;
typedef short bf16x8 __attribute__((ext_vector_type(8)));
typedef float f32x4 __attribute__((ext_vector_type(4)));

// q pre-scale: DIM_HEAD^-0.5 * log2(e)  -> S comes out of MFMA in log2 domain
#define QSCALE 0.18033688011112042f
#define EXPOFF 20.0f   // softmax shift (exact: softmax is shift-invariant)

static __device__ __forceinline__ u16 f2bf(float f) {
    union { float f; u32 u; } v; v.f = f;
    u32 u = v.u;
    u += 0x7fffu + ((u >> 16) & 1u);   // round-to-nearest-even
    return (u16)(u >> 16);
}
static __device__ __forceinline__ float bf2f(u16 h) {
    union { u32 u; float f; } v; v.u = ((u32)h) << 16; return v.f;
}

// async global->LDS, 16 B per lane; LDS dest is wave-uniform base + lane*16.
static __device__ __forceinline__ void gld_lds16(const u16* g, u16* l) {
    __builtin_amdgcn_global_load_lds(
        (__attribute__((address_space(1))) void*)(u64)g,
        (__attribute__((address_space(3))) void*)(u32)(u64)l,
        16, 0, 0);
}

// XOR-swizzle (64-col rows, 8 chunks): LDS[r][c] = G[r][c ^ (r&7)]
#define SWZ_SCOL(lane) ((((lane) & 7) ^ (((lane) >> 3) & 7)) * 8)

// raw barrier / waits: no compiler-attached vmcnt(0) drain (unlike __syncthreads)
#define RAW_BARRIER()   asm volatile("s_barrier" ::: "memory")
#define WAIT_VM0()      asm volatile("s_waitcnt vmcnt(0)" ::: "memory")
#define WAIT_LGKM0()    asm volatile("s_waitcnt lgkmcnt(0)" ::: "memory")

// ------- fused pre-phase: bprep(Wqkv->B1) blocks + gates/A1-expand blocks ----
// blockIdx.x < 192: bprep tile (body identical to bprep_kernel, R=1024,Cg=3072)
// blockIdx.x >= 192: gates+expand (body identical to old gates_expand_kernel)
// Branch is block-uniform; fusing overlaps two memory-bound kernels that were
// serialized on the stream.
__global__ __launch_bounds__(256) void pre_kernel(const float* __restrict__ x,
                                                  const float* __restrict__ Wg,
                                                  const float* __restrict__ Wqkv,
                                                  float* __restrict__ gates,
                                                  u16* __restrict__ outA,
                                                  u16* __restrict__ B1) {
    __shared__ u16 lds[64 * 68];
    const int t = threadIdx.x;
    if (blockIdx.x < 192) {
        // ---- bprep: B1[cg][r*4+w] = bf16(Wqkv[r][cg*4+w]); tile 64r x 16cg
        const int cg0 = blockIdx.x * 16, k0 = blockIdx.y * 64;
        const float4* s4 = (const float4*)Wqkv;  // row stride = 3072 float4s
        for (int i = 0; i < 4; ++i) {
            int f = i * 256 + t;
            int kl = f >> 4, f4 = f & 15;
            float4 v = s4[(size_t)(k0 + kl) * 3072 + cg0 + f4];
            ushort4 o; o.x = f2bf(v.x); o.y = f2bf(v.y); o.z = f2bf(v.z); o.w = f2bf(v.w);
            *(ushort4*)&lds[kl * 68 + f4 * 4] = o;
        }
        __syncthreads();
        ushort4* d4 = (ushort4*)B1;  // row stride = 1024 ushort4s
        for (int i = 0; i < 4; ++i) {
            int j = i * 256 + t;
            int cgl = j >> 6, kl = j & 63;
            d4[(size_t)(cg0 + cgl) * 1024 + k0 + kl] = *(ushort4*)&lds[kl * 68 + cgl * 4];
        }
    } else {
        // ---- gates + A1-expand: one wave per row
        const int wid = t >> 6, lane = t & 63;
        const int gb = (blockIdx.x - 192) * 16 + blockIdx.y;   // 0..1023
        const int m = gb * 4 + wid;
        const float* xr = x + (size_t)m * DIM_;
        float a0 = 0.f, a1 = 0.f, a2 = 0.f, a3 = 0.f;
        for (int i = 0; i < DIM_ / 64; ++i) {
            int k = i * 64 + lane;
            float xv = xr[k];
            float4 wg = ((const float4*)Wg)[k];
            a0 += xv * wg.x; a1 += xv * wg.y; a2 += xv * wg.z; a3 += xv * wg.w;
        }
        for (int s = 1; s < 64; s <<= 1) {
            a0 += __shfl_xor(a0, s); a1 += __shfl_xor(a1, s);
            a2 += __shfl_xor(a2, s); a3 += __shfl_xor(a3, s);
        }
        float mx = fmaxf(fmaxf(a0, a1), fmaxf(a2, a3));
        float e0 = __expf(a0 - mx), e1 = __expf(a1 - mx), e2 = __expf(a2 - mx), e3 = __expf(a3 - mx);
        float inv = 1.0f / (e0 + e1 + e2 + e3);
        float g0 = e0 * inv, g1 = e1 * inv, g2 = e2 * inv, g3 = e3 * inv;
        if (lane == 0) ((float4*)gates)[m] = make_float4(g0, g1, g2, g3);
        ushort4* out4 = (ushort4*)outA;
        for (int i = 0; i < DIM_ / 64; ++i) {
            int k = i * 64 + lane;
            float val = xr[k];   // L1 hit
            ushort4 o;
            o.x = f2bf(val * g0); o.y = f2bf(val * g1); o.z = f2bf(val * g2); o.w = f2bf(val * g3);
            out4[(size_t)m * 1024 + k] = o;
        }
    }
}

// -------- B-prep: dst[cg][r*4+w] = bf16(src[r][cg*4+w]); tile 64r x 16cg ----
// Used for B2 (Wout) only; B2 aliases B1's extent -> MUST launch after gemm1.
__global__ __launch_bounds__(256) void bprep_kernel(const float* __restrict__ src,
                                                    u16* __restrict__ dst,
                                                    int R, int Cg) {
    __shared__ u16 lds[64 * 68];
    const int t = threadIdx.x;
    const int cg0 = blockIdx.x * 16, k0 = blockIdx.y * 64;
    const float4* s4 = (const float4*)src;  // row stride = Cg float4s
    for (int i = 0; i < 4; ++i) {
        int f = i * 256 + t;
        int kl = f >> 4, f4 = f & 15;
        float4 v = s4[(size_t)(k0 + kl) * Cg + cg0 + f4];
        ushort4 o; o.x = f2bf(v.x); o.y = f2bf(v.y); o.z = f2bf(v.z); o.w = f2bf(v.w);
        *(ushort4*)&lds[kl * 68 + f4 * 4] = o;
    }
    __syncthreads();
    ushort4* d4 = (ushort4*)dst;  // row stride = R ushort4s
    for (int i = 0; i < 4; ++i) {
        int j = i * 256 + t;
        int cgl = j >> 6, kl = j & 63;
        d4[(size_t)(cg0 + cgl) * R + k0 + kl] = *(ushort4*)&lds[kl * 68 + cgl * 4];
    }
}

// ---------------- GEMM1: 128x128 tile, BK=64, swizzled LDS ------------------
// Round-0 proven version (142 us, 727 TF). Default blockIdx mapping KEPT:
// round-robin dispatch already gives each XCD fixed n-columns (24%8==0) ->
// B-panel 3 MB/XCD L2-resident. (XCD swizzle measured WORSE here: 217 MB
// fetch vs 160 -- do not re-add. 256^2 deep-pipeline attempts measured 170/168
// vs 142 -- do not re-attempt without per-kernel counter attribution.)
__global__ __launch_bounds__(256) void gemm1_kernel(const u16* __restrict__ A,
                                                    const u16* __restrict__ Bm,
                                                    u16* __restrict__ qbuf,
                                                    u16* __restrict__ kbuf,
                                                    u16* __restrict__ vbuf) {
    __shared__ u16 lA[128 * 64];
    __shared__ u16 lB[128 * 64];
    const int t = threadIdx.x;
    const int lane = t & 63, wid = t >> 6;
    const int wm = wid >> 1, wn = wid & 1;
    const int l15 = lane & 15, quad = lane >> 4;
    const int sx = l15 & 7;
    const int n0 = blockIdx.x * 128, m0 = blockIdx.y * 128;
    const int srow = lane >> 3, scol = SWZ_SCOL(lane);
    const u16* gA = A + (size_t)(m0 + wid * 32 + srow) * KP + scol;
    const u16* gB = Bm + (size_t)(n0 + wid * 32 + srow) * KP + scol;
    u16* lAw = &lA[wid * 2048];
    u16* lBw = &lB[wid * 2048];
    f32x4 acc[4][4] = {};
    for (int k0 = 0; k0 < KP; k0 += 64) {
        for (int i = 0; i < 4; ++i)
            gld_lds16(gA + (size_t)i * 8 * KP + k0, lAw + i * 512);
        for (int i = 0; i < 4; ++i)
            gld_lds16(gB + (size_t)i * 8 * KP + k0, lBw + i * 512);
        __syncthreads();
        for (int ks = 0; ks < 2; ++ks) {
            const int co = ((ks * 4 + quad) ^ sx) * 8;
            bf16x8 af[4], bfr[4];
            for (int mt = 0; mt < 4; ++mt)
                af[mt] = *(const bf16x8*)&lA[(wm * 64 + mt * 16 + l15) * 64 + co];
            for (int nt = 0; nt < 4; ++nt)
                bfr[nt] = *(const bf16x8*)&lB[(wn * 64 + nt * 16 + l15) * 64 + co];
            for (int mt = 0; mt < 4; ++mt)
                for (int nt = 0; nt < 4; ++nt)
                    acc[mt][nt] = __builtin_amdgcn_mfma_f32_16x16x32_bf16(af[mt], bfr[nt], acc[mt][nt], 0, 0, 0);
        }
        __syncthreads();
    }
    const int qkv = n0 >> 10;
    const int base_hd = n0 & 1023;
    for (int mt = 0; mt < 4; ++mt) {
        int mrow = m0 + wm * 64 + mt * 16 + quad * 4;
        int b = mrow >> 11, n = mrow & 2047;
        int bh0 = b * 16;
        for (int nt = 0; nt < 4; ++nt) {
            int hd = base_hd + wn * 64 + nt * 16 + l15;
            int h = hd >> 6, d = hd & 63;
            int bh = bh0 + h;
            if (qkv == 0) {
                for (int r = 0; r < 4; ++r)
                    qbuf[((size_t)bh * 2048 + n + r) * 64 + d] = f2bf(acc[mt][nt][r] * QSCALE);
            } else if (qkv == 1) {
                for (int r = 0; r < 4; ++r)
                    kbuf[((size_t)bh * 2048 + n + r) * 64 + d] = f2bf(acc[mt][nt][r]);
            } else {
                ushort4 o;
                o.x = f2bf(acc[mt][nt][0]); o.y = f2bf(acc[mt][nt][1]);
                o.z = f2bf(acc[mt][nt][2]); o.w = f2bf(acc[mt][nt][3]);
                *(ushort4*)&vbuf[((size_t)bh * 64 + d) * 2048 + n] = o;
            }
        }
    }
}

// ---------------- GEMM2: 128x64 tile, BK=64, DOUBLE-BUFFERED ----------------
// Round-3 proven version. Single raw barrier per iter; prefetch issued BEFORE
// compute -> the vmcnt(0) at the next loop top waits on loads issued one full
// iteration earlier. XCD swizzle: each XCD owns 64 consecutive bids = 4
// contiguous m-rows -> A-panels 4 MB L2-resident.
// (Ring-3 + counted vmcnt measured WORSE: LDS 48->72KB cut block capacity
// 3->2 per CU; do not re-add.)
__global__ __launch_bounds__(256) void gemm2_kernel(const u16* __restrict__ A,
                                                    const u16* __restrict__ Bm,
                                                    float* __restrict__ outf) {
    __shared__ u16 lA[2][128 * 64];   // 32 KB
    __shared__ u16 lB[2][64 * 64];    // 16 KB
    const int t = threadIdx.x;
    const int lane = t & 63, wid = t >> 6;
    const int wm = wid >> 1, wn = wid & 1;
    const int l15 = lane & 15, quad = lane >> 4;
    const int sx = l15 & 7;
    // XCD-bijective swizzle (grid 16x32 = 512)
    const int bid0 = blockIdx.y * 16 + blockIdx.x;
    const int nbid = (bid0 & 7) * 64 + (bid0 >> 3);
    const int n0 = (nbid & 15) * 64, m0 = (nbid >> 4) * 128;
    const int srow = lane >> 3, scol = SWZ_SCOL(lane);
    const u16* gA = A + (size_t)(m0 + wid * 32 + srow) * KP + scol;
    const u16* gB = Bm + (size_t)(n0 + wid * 16 + srow) * KP + scol;
    // prologue: stage k-tile 0 into buf 0
    for (int i = 0; i < 4; ++i)
        gld_lds16(gA + (size_t)i * 8 * KP, &lA[0][(wid * 32 + i * 8) * 64]);
    for (int i = 0; i < 2; ++i)
        gld_lds16(gB + (size_t)i * 8 * KP, &lB[0][(wid * 16 + i * 8) * 64]);
    f32x4 acc[4][2] = {};
    for (int it = 0; it < 64; ++it) {
        const int cur = it & 1;
        WAIT_VM0();       // cur buf resident (issued one iter ago)
        RAW_BARRIER();    // all waves' slices resident; prev iter compute done
        if (it + 1 < 64) {
            const int k0 = (it + 1) * 64, nb = cur ^ 1;
            for (int i = 0; i < 4; ++i)
                gld_lds16(gA + (size_t)i * 8 * KP + k0, &lA[nb][(wid * 32 + i * 8) * 64]);
            for (int i = 0; i < 2; ++i)
                gld_lds16(gB + (size_t)i * 8 * KP + k0, &lB[nb][(wid * 16 + i * 8) * 64]);
        }
        for (int ks = 0; ks < 2; ++ks) {
            const int co = ((ks * 4 + quad) ^ sx) * 8;
            bf16x8 af[4], bfr[2];
            for (int mt = 0; mt < 4; ++mt)
                af[mt] = *(const bf16x8*)&lA[cur][(wm * 64 + mt * 16 + l15) * 64 + co];
            for (int nt = 0; nt < 2; ++nt)
                bfr[nt] = *(const bf16x8*)&lB[cur][(wn * 32 + nt * 16 + l15) * 64 + co];
            for (int mt = 0; mt < 4; ++mt)
                for (int nt = 0; nt < 2; ++nt)
                    acc[mt][nt] = __builtin_amdgcn_mfma_f32_16x16x32_bf16(af[mt], bfr[nt], acc[mt][nt], 0, 0, 0);
        }
    }
    for (int mt = 0; mt < 4; ++mt) {
        int mrow = m0 + wm * 64 + mt * 16 + quad * 4;
        for (int nt = 0; nt < 2; ++nt) {
            int col = n0 + wn * 32 + nt * 16 + l15;
            for (int r = 0; r < 4; ++r)
                outf[(size_t)(mrow + r) * NC2 + col] = acc[mt][nt][r];
        }
    }
}

// ------------- flash attention: BQ=128, BKV=64, DOUBLE-BUFFERED K/V ---------
// Round-3 proven version. S^T = K Q^T; no-max exp2 softmax; wave-private lP +
// lgkm fence; single raw barrier per iter with issue-early prefetch.
// Epilogue writes A2[m][k*4+w] = O[m][hd] * g[m][w] (gated expand fused).
// XCD swizzle: each XCD owns 4 consecutive bh -> K/V set 2 MB, L2-resident.
// (Ring-3 + counted vmcnt measured WORSE: LDS 50->67KB cut block capacity
// 3->2 per CU; do not re-add.)
__global__ __launch_bounds__(256) void attn_kernel(const u16* __restrict__ qbuf,
                                                   const u16* __restrict__ kbuf,
                                                   const u16* __restrict__ vbuf,
                                                   const float* __restrict__ gates,
                                                   u16* __restrict__ outA) {
    __shared__ u16 lK[2][64 * 64];        // 16 KB, swizzled
    __shared__ u16 lV[2][64 * 64];        // 16 KB, swizzled
    __shared__ u16 lP[4][2 * 16 * 72];    // 18 KB: [wave][mt][i=16][j=64 pad 72]
    const int t = threadIdx.x, lane = t & 63, wq = t >> 6;
    const int l15 = lane & 15, quad = lane >> 4;
    const int sx7 = l15 & 7;
    // XCD-bijective swizzle (grid 16x32 = 512)
    const int bid0 = blockIdx.y * 16 + blockIdx.x;
    const int nbid = (bid0 & 7) * 64 + (bid0 >> 3);
    const int bh = nbid >> 4, q0 = (nbid & 15) * 128;
    const u16* Q = qbuf + (size_t)bh * 2048 * 64;
    const u16* K = kbuf + (size_t)bh * 2048 * 64;
    const u16* V = vbuf + (size_t)bh * 64 * 2048;
    // Q fragments (B-operand): direct global loads (qbuf is unswizzled)
    bf16x8 qf[2][2];
    for (int mt = 0; mt < 2; ++mt)
        for (int ks = 0; ks < 2; ++ks)
            qf[mt][ks] = *(const bf16x8*)&Q[(size_t)(q0 + wq * 32 + mt * 16 + l15) * 64 + ks * 32 + quad * 8];
    f32x4 Oa[2][4] = {};
    float lacc[2] = {0.f, 0.f};
    const int krow = lane >> 3, kcol = SWZ_SCOL(lane);
    const u16* gK = K + (size_t)(wq * 16 + krow) * 64 + kcol;
    const u16* gV = V + (size_t)(wq * 16 + krow) * 2048 + kcol;
    u16* lPw = lP[wq];
    // prologue: stage KV tile 0 into buf 0 (wave covers 16 rows of each)
    gld_lds16(gK, &lK[0][(wq * 16) * 64]);
    gld_lds16(gK + (size_t)8 * 64, &lK[0][(wq * 16 + 8) * 64]);
    gld_lds16(gV, &lV[0][(wq * 16) * 64]);
    gld_lds16(gV + (size_t)8 * 2048, &lV[0][(wq * 16 + 8) * 64]);
    for (int kt = 0; kt < 32; ++kt) {
        const int cur = kt & 1;
        WAIT_VM0();       // cur KV tile resident (issued one iter ago)
        RAW_BARRIER();    // all waves resident; prev iter reads of buf^1 done
        if (kt + 1 < 32) {
            const int nxt = (kt + 1) * 64, nb = cur ^ 1;
            gld_lds16(gK + (size_t)nxt * 64, &lK[nb][(wq * 16) * 64]);
            gld_lds16(gK + (size_t)(nxt + 8) * 64, &lK[nb][(wq * 16 + 8) * 64]);
            gld_lds16(gV + nxt, &lV[nb][(wq * 16) * 64]);
            gld_lds16(gV + nxt + (size_t)8 * 2048, &lV[nb][(wq * 16 + 8) * 64]);
        }
        // S^T = K Q^T : D[m=j][n=i]; kf shared across both mt groups
        f32x4 S[2][4] = {};
        for (int ks = 0; ks < 2; ++ks) {
            const int co = ((ks * 4 + quad) ^ sx7) * 8;
            for (int nt = 0; nt < 4; ++nt) {
                bf16x8 kf = *(const bf16x8*)&lK[cur][(nt * 16 + l15) * 64 + co];
                S[0][nt] = __builtin_amdgcn_mfma_f32_16x16x32_bf16(kf, qf[0][ks], S[0][nt], 0, 0, 0);
                S[1][nt] = __builtin_amdgcn_mfma_f32_16x16x32_bf16(kf, qf[1][ks], S[1][nt], 0, 0, 0);
            }
        }
        // P = exp2(S - EXPOFF); lane holds (j=nt*16+quad*4+r, i=l15):
        // 4 consecutive j -> one b64 write at lP[i][j] ([i][j]-major)
        for (int mt = 0; mt < 2; ++mt) {
            u16* lPm = lPw + mt * (16 * 72);
            for (int nt = 0; nt < 4; ++nt) {
                float p0 = __builtin_amdgcn_exp2f(S[mt][nt][0] - EXPOFF);
                float p1 = __builtin_amdgcn_exp2f(S[mt][nt][1] - EXPOFF);
                float p2 = __builtin_amdgcn_exp2f(S[mt][nt][2] - EXPOFF);
                float p3 = __builtin_amdgcn_exp2f(S[mt][nt][3] - EXPOFF);
                lacc[mt] += (p0 + p1) + (p2 + p3);
                uint2 pk;
                pk.x = (u32)f2bf(p0) | ((u32)f2bf(p1) << 16);
                pk.y = (u32)f2bf(p2) | ((u32)f2bf(p3) << 16);
                *(uint2*)&lPm[l15 * 72 + nt * 16 + quad * 4] = pk;
            }
        }
        WAIT_LGKM0();   // drain wave's own ds_writes (wave-private lP)
        // O += P V
        for (int ks = 0; ks < 2; ++ks) {
            const int co = ((ks * 4 + quad) ^ sx7) * 8;
            bf16x8 p0 = *(const bf16x8*)&lPw[0 * (16 * 72) + l15 * 72 + ks * 32 + quad * 8];
            bf16x8 p1 = *(const bf16x8*)&lPw[1 * (16 * 72) + l15 * 72 + ks * 32 + quad * 8];
            for (int dt = 0; dt < 4; ++dt) {
                bf16x8 vf = *(const bf16x8*)&lV[cur][(dt * 16 + l15) * 64 + co];
                Oa[0][dt] = __builtin_amdgcn_mfma_f32_16x16x32_bf16(p0, vf, Oa[0][dt], 0, 0, 0);
                Oa[1][dt] = __builtin_amdgcn_mfma_f32_16x16x32_bf16(p1, vf, Oa[1][dt], 0, 0, 0);
            }
        }
    }
    // final row-sum reduce across quads (lanes l15, l15+16, l15+32, l15+48)
    for (int mt = 0; mt < 2; ++mt) {
        lacc[mt] += __shfl_xor(lacc[mt], 16);
        lacc[mt] += __shfl_xor(lacc[mt], 32);
    }
    const int b = bh >> 4, h = bh & 15;
    ushort4* out4 = (ushort4*)outA;
    const float4* gates4 = (const float4*)gates;
    for (int mt = 0; mt < 2; ++mt) {
        for (int r = 0; r < 4; ++r) {
            int n = q0 + wq * 32 + mt * 16 + quad * 4 + r;
            int m = b * 2048 + n;
            float invl = 1.0f / __shfl(lacc[mt], quad * 4 + r);
            float4 g = gates4[m];
            for (int dt = 0; dt < 4; ++dt) {
                float val = Oa[mt][dt][r] * invl;
                ushort4 o;
                o.x = f2bf(val * g.x); o.y = f2bf(val * g.y);
                o.z = f2bf(val * g.z); o.w = f2bf(val * g.w);
                out4[(size_t)m * 1024 + h * 64 + dt * 16 + l15] = o;
            }
        }
    }
}

extern "C" void kernel_launch(void* const* d_in, const int* in_sizes, int n_in,
                              void* d_out, int out_size, void* d_ws, size_t ws_size,
                              hipStream_t stream) {
    const float* x    = (const float*)d_in[0];
    const float* Wqkv = (const float*)d_in[1];
    const float* Wg   = (const float*)d_in[2];
    const float* Wout = (const float*)d_in[3];
    // d_in[4] = mask: all-true in this problem.

    char* ws = (char*)d_ws;
    size_t off = 0;
    float* gates = (float*)(ws + off); off += (size_t)1 << 16;                 // 64 KB
    u16* Aexp = (u16*)(ws + off);      off += (size_t)M_TOT * KP * 2;          // 32 MB (A1; attn overwrites -> A2)
    char* regB = ws + off;             off += (size_t)NC1 * KP * 2;            // 24 MB
    u16* B1 = (u16*)regB;
    u16* B2 = (u16*)(regB + (size_t)M_TOT * NC2 * 2);                          // aliases B1[8M:16M], WRITTEN AFTER GEMM1
    u16* qbuf = (u16*)(ws + off); off += (size_t)32 * 2048 * 64 * 2;           // 8 MB
    u16* kbuf = (u16*)(ws + off); off += (size_t)32 * 2048 * 64 * 2;           // 8 MB
    u16* vbuf = (u16*)(ws + off); off += (size_t)32 * 2048 * 64 * 2;           // 8 MB

    // fused pre-phase: bprep(Wqkv->B1) blocks [x<192] + gates/A1-expand [x>=192]
    hipLaunchKernelGGL(pre_kernel, dim3(256, 16), dim3(256), 0, stream,
                       x, Wg, Wqkv, gates, Aexp, B1);
    hipLaunchKernelGGL(gemm1_kernel, dim3(24, 32), dim3(256), 0, stream,
                       Aexp, B1, qbuf, kbuf, vbuf);
    hipLaunchKernelGGL(bprep_kernel, dim3(64, 16), dim3(256), 0, stream,
                       Wout, B2, 1024, 1024);   // after gemm1: B2 overlaps B1
    hipLaunchKernelGGL(attn_kernel, dim3(16, 32), dim3(256), 0, stream,
                       qbuf, kbuf, vbuf, gates, Aexp);   // writes A2 (gated expand fused)
    hipLaunchKernelGGL(gemm2_kernel, dim3(16, 32), dim3(256), 0, stream,
                       Aexp, B2, (float*)d_out);
}